// Round 7
// baseline (591.274 us; speedup 1.0000x reference)
//
#include <hip/hip_runtime.h>

#define ALPHA 0.5f
#define BSHIFT 9                 // 512 rows per bucket (586 buckets -> full machine for build)
#define RPB 512
#define NBMAX 640                // >= nBuckets (586)
#define PCHUNK 32768             // edges per scatter chunk: 32768/586 = 56-edge runs = 448B (r0-proven)

// ---------------- bf16 helpers ----------------

__device__ __forceinline__ float bf2f(unsigned short u) {
  return __uint_as_float((unsigned)u << 16);
}
__device__ __forceinline__ unsigned short f2bf(float f) {
  unsigned u = __float_as_uint(f);
  u += 0x7fffu + ((u >> 16) & 1u);   // round-to-nearest-even
  return (unsigned short)(u >> 16);
}

// ---------------- per-chunk bucket histograms ----------------
// histG[c*nb + b] = count of chunk c's edges in bucket b (chunk-major: coalesced)

__global__ __launch_bounds__(1024) void k_hist(
    const int* __restrict__ rows, int nnz, int* __restrict__ histG, int nb) {
  __shared__ int lcnt[NBMAX];
  int t = threadIdx.x;
  if (t < nb) lcnt[t] = 0;
  __syncthreads();
  int base = blockIdx.x * PCHUNK;
  int end = nnz < base + PCHUNK ? nnz : base + PCHUNK;
  for (int e = base + t; e < end; e += 1024)
    atomicAdd(&lcnt[rows[e] >> BSHIFT], 1);
  __syncthreads();
  if (t < nb) histG[(size_t)blockIdx.x * nb + t] = lcnt[t];
}

// ---------------- scan: histG -> within-bucket exclusive offsets; totals -> bptr ----------------
// thread b serially scans bucket b across chunks (coalesced across threads at each step)

__global__ __launch_bounds__(1024) void k_scanh(
    int* __restrict__ histG, int nb, int nchunks, int nnz, int* __restrict__ bptr) {
  __shared__ int tot[1024];
  int t = threadIdx.x;
  int total = 0;
  if (t < nb) {
    for (int c = 0; c < nchunks; c++) {
      int idx = c * nb + t;
      int v = histG[idx];
      histG[idx] = total;        // within-bucket exclusive offset for chunk c
      total += v;
    }
  }
  tot[t] = (t < nb) ? total : 0;
  __syncthreads();
  for (int d = 1; d < 1024; d <<= 1) {
    int x = (t >= d) ? tot[t - d] : 0;
    __syncthreads();
    tot[t] += x;
    __syncthreads();
  }
  if (t < nb) bptr[t] = tot[t] - total;   // exclusive bucket base
  if (t == 0) bptr[nb] = nnz;
}

// ---------------- fused: scatter into buckets (blocks < PB) + f32->bf16 convert ----------------
// Single LDS pass (cursor only); bases precomputed by k_hist/k_scanh.
// pay.x = rowLocal(9b) << 20 | col(19b)

__global__ __launch_bounds__(1024) void k_scatter_conv(
    const int* __restrict__ rows, const int* __restrict__ cols, const float* __restrict__ vals,
    int nnz, int nb, const int* __restrict__ bptr, const int* __restrict__ histG,
    uint2* __restrict__ pPay, int PB,
    const float* __restrict__ uE, const float* __restrict__ iE,
    int nU64, int nTot, unsigned short* __restrict__ out) {
  __shared__ int lbase[NBMAX];
  __shared__ int lcnt[NBMAX];
  int t = threadIdx.x;
  if ((int)blockIdx.x < PB) {
    if (t < nb) {
      lbase[t] = bptr[t] + histG[(size_t)blockIdx.x * nb + t];
      lcnt[t] = 0;
    }
    __syncthreads();
    int base = blockIdx.x * PCHUNK;
    int end = nnz < base + PCHUNK ? nnz : base + PCHUNK;
    for (int e = base + t; e < end; e += 1024) {
      int r = rows[e];
      int b = r >> BSHIFT;
      int p = lbase[b] + atomicAdd(&lcnt[b], 1);
      uint2 pay;
      pay.x = ((unsigned)(r & (RPB - 1)) << 20) | (unsigned)cols[e];
      pay.y = __float_as_uint(vals[e]);
      pPay[p] = pay;
    }
  } else {
    int i = (((int)blockIdx.x - PB) * 1024 + t) * 4;
    if (i >= nTot) return;
    const float* src = (i < nU64) ? (uE + i) : (iE + (i - nU64));
    float4 v = *(const float4*)src;
    ushort4 o;
    o.x = f2bf(v.x); o.y = f2bf(v.y); o.z = f2bf(v.z); o.w = f2bf(v.w);
    *(ushort4*)(out + i) = o;
  }
}

// ---------------- per-bucket CSR build + degree histogram ----------------
// 586 blocks x 1024 thr (2 blocks/CU): full machine, 8.5K edges/block.

__global__ __launch_bounds__(1024) void k_build_csr(
    const int* __restrict__ bptr, const uint2* __restrict__ pPay, int N,
    int* __restrict__ rowptr, int* __restrict__ cnt, int2* __restrict__ colval,
    int* __restrict__ degHist) {
  __shared__ int lcnt[RPB];        // 2 KB: counts -> cursors
  __shared__ int scanbuf[RPB];
  __shared__ int ldeg[256];
  int t = threadIdx.x;
  int b = blockIdx.x;
  int r0 = b << BSHIFT;
  int rCount = N - r0; if (rCount > RPB) rCount = RPB;
  int eBeg = bptr[b], eEnd = bptr[b + 1];

  if (t < RPB) lcnt[t] = 0;
  if (t < 256) ldeg[t] = 0;
  __syncthreads();
  for (int e = eBeg + t; e < eEnd; e += 1024)
    atomicAdd(&lcnt[pPay[e].x >> 20], 1);
  __syncthreads();
  int c0 = 0;
  if (t < rCount) {
    c0 = lcnt[t];
    cnt[r0 + t] = c0;
    atomicAdd(&ldeg[c0 < 255 ? c0 : 255], 1);
  }
  // exclusive scan of lcnt[0..RPB) using first RPB threads
  int s = 0;
  if (t < RPB) { s = lcnt[t]; scanbuf[t] = s; }
  __syncthreads();
  for (int d = 1; d < RPB; d <<= 1) {
    int x = (t >= d && t < RPB) ? scanbuf[t - d] : 0;
    __syncthreads();
    if (t < RPB) scanbuf[t] += x;
    __syncthreads();
  }
  if (t < RPB) lcnt[t] = scanbuf[t] - s;   // exclusive
  __syncthreads();
  if (t < 256 && ldeg[t]) atomicAdd(&degHist[t], ldeg[t]);
  if (t < rCount) rowptr[r0 + t] = eBeg + lcnt[t];
  __syncthreads();
  for (int e = eBeg + t; e < eEnd; e += 1024) {
    uint2 pay = pPay[e];
    int r = (int)(pay.x >> 20);
    int p = eBeg + atomicAdd(&lcnt[r], 1);
    int2 cv; cv.x = (int)(pay.x & 0xFFFFFu); cv.y = (int)pay.y;
    colval[p] = cv;
  }
}

// ---------------- degree-bin scan (1 block) + colval pad init ----------------

__global__ void k_degscan(const int* __restrict__ degHist, int* __restrict__ degCur,
                          int2* __restrict__ colval, int nnz) {
  __shared__ int s[256];
  int t = threadIdx.x;
  int v = degHist[t];
  s[t] = v; __syncthreads();
  for (int d = 1; d < 256; d <<= 1) {
    int x = (t >= d) ? s[t - d] : 0;
    __syncthreads();
    s[t] += x;
    __syncthreads();
  }
  degCur[t] = s[t] - v;   // exclusive
  if (t < 8) { int2 z; z.x = 0; z.y = 0; colval[nnz + t] = z; }
}

// ---------------- permute rows into degree-sorted order ----------------

__global__ __launch_bounds__(256) void k_permute(
    const int* __restrict__ rowptr, const int* __restrict__ cnt, int N,
    int* __restrict__ degCur,
    int* __restrict__ perm, int* __restrict__ rowptrS, int* __restrict__ lenS) {
  __shared__ int lcnt[256];
  __shared__ int lbase[256];
  int t = threadIdx.x;
  lcnt[t] = 0;
  __syncthreads();
  int base = blockIdx.x * 1024;
  int end = N < base + 1024 ? N : base + 1024;
  for (int r = base + t; r < end; r += 256) {
    int c = cnt[r];
    atomicAdd(&lcnt[c < 255 ? c : 255], 1);
  }
  __syncthreads();
  {
    int c = lcnt[t];
    lbase[t] = c ? atomicAdd(&degCur[t], c) : 0;
    lcnt[t] = 0;
  }
  __syncthreads();
  for (int r = base + t; r < end; r += 256) {
    int c = cnt[r];
    int bin = c < 255 ? c : 255;
    int pos = lbase[bin] + atomicAdd(&lcnt[bin], 1);
    perm[pos] = r;
    rowptrS[pos] = rowptr[r];
    lenS[pos] = c;
  }
}

// ---------------- SpMM core: quarter-wave owns 2 degree-adjacent rows ----------------
// (round-0 proven body; pipeline/unroll variants measured slower in r1/r2)

__device__ __forceinline__ void spmm_body(
    int gtid,
    const unsigned short* __restrict__ src,
    const float* __restrict__ e0U, const float* __restrict__ e0I, int split,
    const int* __restrict__ perm, const int* __restrict__ rowptrS, const int* __restrict__ lenS,
    const int2* __restrict__ colval,
    unsigned short* __restrict__ dst, int n) {
  int wave = gtid >> 6;
  int lane = gtid & 63;
  int sub = lane >> 4;
  int k   = lane & 15;
  int q = wave * 4 + sub;
  int s0 = 2 * q, s1 = 2 * q + 1;
  bool va = s0 < n, vb = s1 < n;
  int i0 = va ? s0 : 0, i1 = vb ? s1 : 0;
  int row0 = perm[i0], row1 = perm[i1];
  int st0 = rowptrS[i0], st1 = rowptrS[i1];
  int len0 = va ? lenS[i0] : 0, len1 = vb ? lenS[i1] : 0;
  const int2* cv0 = colval + st0;
  const int2* cv1 = colval + st1;
  const unsigned short* srcK = src + (size_t)k * 4;
  int l0m = len0 > 0 ? len0 - 1 : 0;
  int l1m = len1 > 0 ? len1 - 1 : 0;
  int mx = max(len0, len1);

  float p0 = 0.f, p1 = 0.f, p2 = 0.f, p3 = 0.f;   // row0
  float r0a = 0.f, r1a = 0.f, r2a = 0.f, r3a = 0.f; // row1
  for (int j = 0; j < mx; j += 2) {
    int ja = j, jb = j + 1;
    int j0a = ja < l0m ? ja : l0m, j0b = jb < l0m ? jb : l0m;
    int j1a = ja < l1m ? ja : l1m, j1b = jb < l1m ? jb : l1m;
    int2 e0a = cv0[j0a];
    int2 e0b = cv0[j0b];
    int2 e1a = cv1[j1a];
    int2 e1b = cv1[j1b];
    ushort4 x0a = *(const ushort4*)(srcK + (size_t)e0a.x * 64);
    ushort4 x0b = *(const ushort4*)(srcK + (size_t)e0b.x * 64);
    ushort4 x1a = *(const ushort4*)(srcK + (size_t)e1a.x * 64);
    ushort4 x1b = *(const ushort4*)(srcK + (size_t)e1b.x * 64);
    float w0a = ja < len0 ? __int_as_float(e0a.y) : 0.f;
    float w0b = jb < len0 ? __int_as_float(e0b.y) : 0.f;
    float w1a = ja < len1 ? __int_as_float(e1a.y) : 0.f;
    float w1b = jb < len1 ? __int_as_float(e1b.y) : 0.f;
    p0 = fmaf(w0a, bf2f(x0a.x), p0); p1 = fmaf(w0a, bf2f(x0a.y), p1);
    p2 = fmaf(w0a, bf2f(x0a.z), p2); p3 = fmaf(w0a, bf2f(x0a.w), p3);
    p0 = fmaf(w0b, bf2f(x0b.x), p0); p1 = fmaf(w0b, bf2f(x0b.y), p1);
    p2 = fmaf(w0b, bf2f(x0b.z), p2); p3 = fmaf(w0b, bf2f(x0b.w), p3);
    r0a = fmaf(w1a, bf2f(x1a.x), r0a); r1a = fmaf(w1a, bf2f(x1a.y), r1a);
    r2a = fmaf(w1a, bf2f(x1a.z), r2a); r3a = fmaf(w1a, bf2f(x1a.w), r3a);
    r0a = fmaf(w1b, bf2f(x1b.x), r0a); r1a = fmaf(w1b, bf2f(x1b.y), r1a);
    r2a = fmaf(w1b, bf2f(x1b.z), r2a); r3a = fmaf(w1b, bf2f(x1b.w), r3a);
  }
  if (va) {
    const float* e0p = (row0 < split) ? (e0U + (size_t)row0 * 64)
                                      : (e0I + (size_t)(row0 - split) * 64);
    float4 ev = *(const float4*)(e0p + k * 4);
    ushort4 o;
    o.x = f2bf(p0 + ALPHA * ev.x);
    o.y = f2bf(p1 + ALPHA * ev.y);
    o.z = f2bf(p2 + ALPHA * ev.z);
    o.w = f2bf(p3 + ALPHA * ev.w);
    *(ushort4*)(dst + (size_t)row0 * 64 + k * 4) = o;
  }
  if (vb) {
    const float* e0p = (row1 < split) ? (e0U + (size_t)row1 * 64)
                                      : (e0I + (size_t)(row1 - split) * 64);
    float4 ev = *(const float4*)(e0p + k * 4);
    ushort4 o;
    o.x = f2bf(r0a + ALPHA * ev.x);
    o.y = f2bf(r1a + ALPHA * ev.y);
    o.z = f2bf(r2a + ALPHA * ev.z);
    o.w = f2bf(r3a + ALPHA * ev.w);
    *(ushort4*)(dst + (size_t)row1 * 64 + k * 4) = o;
  }
}

// ---------------- layer-1 SpMM + fused needed-row marking ----------------

__global__ __launch_bounds__(256) void k_spmm1_mark(
    const unsigned short* __restrict__ src,
    const float* __restrict__ e0U, const float* __restrict__ e0I, int split,
    const int* __restrict__ perm, const int* __restrict__ rowptrS, const int* __restrict__ lenS,
    const int2* __restrict__ colval,
    unsigned short* __restrict__ dst, int n, int MB,
    const int* __restrict__ users, const int* __restrict__ items, int B,
    const int* __restrict__ rowptr, const int* __restrict__ cnt,
    unsigned char* __restrict__ flag) {
  if ((int)blockIdx.x < MB) {
    int t = (int)blockIdx.x * 256 + threadIdx.x;
    int wave = t >> 6;
    int lane = t & 63;
    int sub = lane >> 4;
    int k = lane & 15;
    int idx = wave * 4 + sub;
    if (idx >= 2 * B) return;
    int row = (idx < B) ? users[idx] : split + items[idx - B];
    if (k == 0) flag[row] = 1;
    int start = rowptr[row], len = cnt[row];
    for (int j = k; j < len; j += 16) flag[colval[start + j].x] = 1;
  } else {
    spmm_body((int)((blockIdx.x - MB) * 256 + threadIdx.x), src, e0U, e0I, split,
              perm, rowptrS, lenS, colval, dst, n);
  }
}

// ---------------- compact degree-sorted perm list to flagged rows ----------------

__global__ __launch_bounds__(1024) void k_compact(
    const int* __restrict__ perm, const int* __restrict__ rowptrS, const int* __restrict__ lenS,
    const unsigned char* __restrict__ flag, int N, int* __restrict__ selTotal,
    int* __restrict__ selPerm, int* __restrict__ selRowptrS, int* __restrict__ selLenS) {
  __shared__ int sbuf[1024];
  __shared__ int sbase;
  int t = threadIdx.x;
  int i = (int)blockIdx.x * 1024 + t;
  int f = 0, r = 0, rp = 0, ln = 0;
  if (i < N) {
    r = perm[i];
    f = flag[r];
    if (f) { rp = rowptrS[i]; ln = lenS[i]; }
  }
  sbuf[t] = f; __syncthreads();
  for (int d = 1; d < 1024; d <<= 1) {
    int x = (t >= d) ? sbuf[t - d] : 0;
    __syncthreads();
    sbuf[t] += x;
    __syncthreads();
  }
  int incl = sbuf[t];
  if (t == 1023) sbase = atomicAdd(selTotal, incl);
  __syncthreads();
  if (f) {
    int pos = sbase + incl - 1;
    selPerm[pos] = r;
    selRowptrS[pos] = rp;
    selLenS[pos] = ln;
  }
}

// spmm layer-2 (flagged rows only) + fused accA: acc = E0_f32[sample] + 3*bf2f(ebA[sample])
__global__ __launch_bounds__(256) void k_spmm2_acc(
    const unsigned short* __restrict__ ebA,
    const float* __restrict__ e0U, const float* __restrict__ e0I, int split,
    const int* __restrict__ selPerm, const int* __restrict__ selRowptrS,
    const int* __restrict__ selLenS, const int* __restrict__ nSelPtr,
    const int2* __restrict__ colval,
    unsigned short* __restrict__ ebB, int spmmBlocks,
    const int* __restrict__ users, const int* __restrict__ items, int B,
    const float* __restrict__ user_emb, const float* __restrict__ item_emb,
    float* __restrict__ accU, float* __restrict__ accI) {
  if ((int)blockIdx.x < spmmBlocks) {
    int nSel = *nSelPtr;
    spmm_body((int)(blockIdx.x * 256 + threadIdx.x), ebA, e0U, e0I, split,
              selPerm, selRowptrS, selLenS, colval, ebB, nSel);
  } else {
    int t = ((int)blockIdx.x - spmmBlocks) * 256 + threadIdx.x;
    int total = B * 64;
    if (t < total) {
      int b = t >> 6, d = t & 63;
      size_t idx = (size_t)users[b] * 64 + d;
      accU[t] = user_emb[idx] + 3.f * bf2f(ebA[idx]);
    } else if (t < 2 * total) {
      int t2 = t - total;
      int b = t2 >> 6, d = t2 & 63;
      int r = items[b];
      accI[t2] = item_emb[(size_t)r * 64 + d] + 3.f * bf2f(ebA[(size_t)(split + r) * 64 + d]);
    }
  }
}

// ---------------- fused layer-3 mini-SpMM + 2*E2 term (8192 sampled rows) ----------------

__global__ __launch_bounds__(256) void k_mini3(
    const int* __restrict__ users, const int* __restrict__ items, int B, int split,
    const unsigned short* __restrict__ ebB,
    const float* __restrict__ e0U, const float* __restrict__ e0I,
    const int* __restrict__ rowptr, const int* __restrict__ cnt,
    const int2* __restrict__ colval,
    float* __restrict__ accU, float* __restrict__ accI) {
  int wave = (int)((blockIdx.x * blockDim.x + threadIdx.x) >> 6);
  int lane = threadIdx.x & 63;
  int sub = lane >> 4;
  int k   = lane & 15;
  int idx = wave * 4 + sub;
  bool valid = idx < 2 * B;
  int ic = valid ? idx : 0;
  int row;
  float* accp;
  if (ic < B) { row = users[ic];             accp = accU + (size_t)ic * 64; }
  else        { row = split + items[ic - B]; accp = accI + (size_t)(ic - B) * 64; }
  int start = rowptr[row];
  int len   = valid ? cnt[row] : 0;
  int maxlen = len;
  maxlen = max(maxlen, __shfl_xor(maxlen, 16));
  maxlen = max(maxlen, __shfl_xor(maxlen, 32));
  const int2* cv = colval + start;
  const unsigned short* srcK = ebB + (size_t)k * 4;

  float a0 = 0.f, a1 = 0.f, a2 = 0.f, a3 = 0.f;
  for (int j = 0; j < maxlen; j += 4) {
#pragma unroll
    for (int u = 0; u < 4; u++) {
      int jj = j + u;
      if (jj < len) {
        int2 e = cv[jj];
        float v = __int_as_float(e.y);
        ushort4 x = *(const ushort4*)(srcK + (size_t)e.x * 64);
        a0 = fmaf(v, bf2f(x.x), a0);
        a1 = fmaf(v, bf2f(x.y), a1);
        a2 = fmaf(v, bf2f(x.z), a2);
        a3 = fmaf(v, bf2f(x.w), a3);
      }
    }
  }
  if (valid) {
    const float* e0p = (row < split) ? (e0U + (size_t)row * 64)
                                     : (e0I + (size_t)(row - split) * 64);
    float4 ev = *(const float4*)(e0p + k * 4);
    ushort4 x2 = *(const ushort4*)(srcK + (size_t)row * 64);  // E2[row], fused 2x term
    float4 cur = *(const float4*)(accp + k * 4);
    cur.x += a0 + ALPHA * ev.x + 2.f * bf2f(x2.x);
    cur.y += a1 + ALPHA * ev.y + 2.f * bf2f(x2.y);
    cur.z += a2 + ALPHA * ev.z + 2.f * bf2f(x2.z);
    cur.w += a3 + ALPHA * ev.w + 2.f * bf2f(x2.w);
    *(float4*)(accp + k * 4) = cur;
  }
}

__global__ void k_dot(const float* __restrict__ accU, const float* __restrict__ accI, int B,
                      float* __restrict__ out) {
  int wave = (int)((blockIdx.x * blockDim.x + threadIdx.x) >> 6);
  int lane = threadIdx.x & 63;
  if (wave >= B) return;
  float p = accU[(size_t)wave * 64 + lane] * accI[(size_t)wave * 64 + lane];
  for (int d = 32; d > 0; d >>= 1) p += __shfl_xor(p, d);
  if (lane == 0) out[wave] = p * (1.f / 16.f);  // (1/4) layer mean x (1/4) weight norm
}

// ---------------- launch ----------------

extern "C" void kernel_launch(void* const* d_in, const int* in_sizes, int n_in,
                              void* d_out, int out_size, void* d_ws, size_t ws_size,
                              hipStream_t stream) {
  const int*   users     = (const int*)d_in[0];
  const int*   items     = (const int*)d_in[1];
  const int*   rows      = (const int*)d_in[2];
  const int*   cols      = (const int*)d_in[3];
  const float* vals      = (const float*)d_in[4];
  const float* user_emb  = (const float*)d_in[5];
  const float* item_emb  = (const float*)d_in[6];
  const float* user_emb0 = (const float*)d_in[7];
  const float* item_emb0 = (const float*)d_in[8];
  float* gamma = (float*)d_out;

  int B   = in_sizes[0];
  int nnz = in_sizes[2];
  int nU  = in_sizes[5] / 64;
  int nI  = in_sizes[6] / 64;
  int N   = nU + nI;
  int nb  = (N + RPB - 1) >> BSHIFT;   // 586 buckets
  int PB  = (nnz + PCHUNK - 1) / PCHUNK;   // 153 chunks
  int Nf  = (N + 15) & ~15;            // flag bytes, 16B aligned

  char* base = (char*)d_ws;
  unsigned short* ebIn = (unsigned short*)base;          // N*64 bf16
  unsigned short* ebA  = ebIn + (size_t)N * 64;          // N*64 bf16 (layer-1 out)
  unsigned short* ebB  = ebA  + (size_t)N * 64;          // N*64 bf16 (layer-2 out, flagged rows only)
  uint2* pPay = (uint2*)ebA;                             // overlay: dead before layer-1 spmm
  char* p = (char*)(ebB + (size_t)N * 64);
  int2* colval  = (int2*)p;           p += ((size_t)nnz + 8) * sizeof(int2);
  int*  rowptr  = (int*)p;            p += (size_t)N * sizeof(int);
  int*  cnt     = (int*)p;            p += (size_t)N * sizeof(int);
  int*  perm    = (int*)p;            p += (size_t)N * sizeof(int);
  int*  rowptrS = (int*)p;            p += (size_t)N * sizeof(int);
  int*  lenS    = (int*)p;            p += (size_t)N * sizeof(int);
  int*  selPerm    = (int*)p;         p += (size_t)N * sizeof(int);
  int*  selRowptrS = (int*)p;         p += (size_t)N * sizeof(int);
  int*  selLenS    = (int*)p;         p += (size_t)N * sizeof(int);
  int*  histG   = (int*)p;            p += (size_t)PB * nb * sizeof(int);
  int*  bptr    = (int*)p;            p += (nb + 1) * sizeof(int);
  // zeroed region (one memset): degHist, selTotal(+pad), flag
  int*  degHist = (int*)p;            p += 256 * sizeof(int);
  int*  selTotal= (int*)p;            p += 4 * sizeof(int);
  unsigned char* flag = (unsigned char*)p; p += Nf;
  int*  degCur  = (int*)p;            p += 256 * sizeof(int);
  float* accU   = (float*)p;          p += (size_t)B * 64 * sizeof(float);
  float* accI   = (float*)p;          p += (size_t)B * 64 * sizeof(float);

  hipMemsetAsync(degHist, 0, (256 + 4) * sizeof(int) + Nf, stream);

  const int tpb = 256;
  int nTot = N * 64;

  // two-pass bucket sort: per-chunk hists -> bases -> single-pass scatter
  k_hist<<<PB, 1024, 0, stream>>>(rows, nnz, histG, nb);
  k_scanh<<<1, 1024, 0, stream>>>(histG, nb, PB, nnz, bptr);

  int convB = (nTot / 4 + 1023) / 1024;
  k_scatter_conv<<<PB + convB, 1024, 0, stream>>>(rows, cols, vals, nnz, nb, bptr, histG,
                                                  pPay, PB, user_emb, item_emb,
                                                  nU * 64, nTot, ebIn);

  k_build_csr<<<nb, 1024, 0, stream>>>(bptr, pPay, N, rowptr, cnt, colval, degHist);
  k_degscan<<<1, 256, 0, stream>>>(degHist, degCur, colval, nnz);
  k_permute<<<(N + 1023) / 1024, tpb, 0, stream>>>(rowptr, cnt, N, degCur, perm, rowptrS, lenS);

  // 32 rows per 256-thread block (4 waves x 4 quarters x 2 rows)
  int spmmBlocks = (N + 31) / 32;
  int accBlocks = (2 * B * 64 + tpb - 1) / tpb;
  int markBlocks = (2 * B + 15) / 16;            // 512

  // layer 1 (all rows) + fused marking of ebB-needed rows (pPay dead from here)
  k_spmm1_mark<<<markBlocks + spmmBlocks, tpb, 0, stream>>>(
      ebIn, user_emb0, item_emb0, nU, perm, rowptrS, lenS, colval, ebA, N,
      markBlocks, users, items, B, rowptr, cnt, flag);

  // compact degree-sorted list to flagged rows (~38% of N)
  k_compact<<<(N + 1023) / 1024, 1024, 0, stream>>>(perm, rowptrS, lenS, flag, N,
                                                    selTotal, selPerm, selRowptrS, selLenS);

  // layer 2 on flagged rows only + fused accA (E0 + 3*E1 at sampled rows)
  k_spmm2_acc<<<spmmBlocks + accBlocks, tpb, 0, stream>>>(
      ebA, user_emb0, item_emb0, nU, selPerm, selRowptrS, selLenS, selTotal,
      colval, ebB, spmmBlocks, users, items, B, user_emb, item_emb, accU, accI);

  // layer 3 sampled rows + fused 2*E2 term
  int mBlocks = (2 * B + 15) / 16;
  k_mini3<<<mBlocks, tpb, 0, stream>>>(users, items, B, nU, ebB,
                                       user_emb0, item_emb0,
                                       rowptr, cnt, colval, accU, accI);

  k_dot<<<(B * 64 + tpb - 1) / tpb, tpb, 0, stream>>>(accU, accI, B, gamma);
}